// Round 1
// 96.148 us; speedup vs baseline: 1.0504x; 1.0504x over previous
//
#include <hip/hip_runtime.h>

// Problem constants
#define NXC 21
#define NDR 5
#define NFEAT 27          // 1 con + 21 x + 5 drug
#define NTERMS 568        // 1 + 21 + 105 + 210 + 210 + 21
// coefficient table layout (LDS, per block):
//  [0]        c0 (constant term)
//  [1..21]    LX[i]  (linear-in-x coeffs)
//  [22..42]   LY[i]  (hill coeffs, applied to y_i = x_i/(0.5+x_i))
//  [43..147]  D[d*21+i] (drug coeffs)
//  [148..567] BM interleaved: pair k (lexicographic i<j): [148+2k]=bilin, [148+2k+1]=mm2
#define OFF_LX 1
#define OFF_LY 22
#define OFF_D  43
#define OFF_BM 148
#define NCOEF  568

// 512 points per block, 2 points per thread.
#define PTS_PER_BLOCK 512
#define LDS_F4 ((PTS_PER_BLOCK * NFEAT) / 4)   // 3456 float4 = 55296 B

// Direct global->LDS DMA, 16 B per lane (linear dest = the supported pattern).
#define GLOBAL_TO_LDS16(gp, lp)                                              \
    __builtin_amdgcn_global_load_lds(                                        \
        (const __attribute__((address_space(1))) void*)(gp),                 \
        (__attribute__((address_space(3))) void*)(lp), 16, 0, 0)

__global__ __launch_bounds__(256) void sindy_fused(
    const float* __restrict__ cand,
    const float* __restrict__ a,
    const int* __restrict__ lin_idx,
    const int* __restrict__ drug_idx,
    const int* __restrict__ bilin_idx,
    const int* __restrict__ mm2_idx,
    const int* __restrict__ hill_idx,
    const void* __restrict__ uses_self,
    float* __restrict__ out)
{
    __shared__ __align__(16) float sx[PTS_PER_BLOCK * NFEAT];   // 55296 B
    __shared__ __align__(16) float scf[NCOEF];                  //  2272 B

    const int tid = threadIdx.x;
    const size_t base = (size_t)blockIdx.x * PTS_PER_BLOCK;

    // ---- Phase 1: issue candidate staging (global -> LDS, no VGPR round-trip).
    // Block's region is 55296 B = 3456 float4 = 13.5 rounds of 256 lanes.
    const float4* g4 = (const float4*)(cand + base * NFEAT);   // 16B-aligned: 55296 % 16 == 0
    float4* s4 = (float4*)sx;
#pragma unroll
    for (int k = 0; k < 13; ++k) {
        const int idx = tid + k * 256;
        GLOBAL_TO_LDS16(g4 + idx, s4 + idx);
    }
    if (tid < (LDS_F4 - 13 * 256)) {          // 128 lanes = 2 full waves (wave-uniform exec)
        const int idx = tid + 13 * 256;
        GLOBAL_TO_LDS16(g4 + idx, s4 + idx);
    }

    // ---- Phase 2 (overlaps the in-flight staging): coefficient table into LDS.
    // 2a: uses_self storage detect, wave-parallel (replaces thread-0 serial scan).
    //   byte storage  -> some packed word has a byte set in lanes 1..3  (>1, != 1.0f bits)
    //   int32 {0,1}   -> all scanned words in {0,1}
    //   float32       -> words in {0, 0x3f800000}
    //   word modes unify: us = (word != 0) is correct for both int32 and float32 bools.
    const unsigned int* u32 = (const unsigned int*)uses_self;
    const int lane = tid & 63;
    bool bad_byte = false;
#pragma unroll
    for (int r = 0; r < 3; ++r) {
        const int j = lane + r * 64;          // covers 0..191 >= 142 words
        if (j < NTERMS / 4) {
            const unsigned int v = u32[j];
            if (v > 1u && v != 0x3f800000u) bad_byte = true;
        }
    }
    const bool bytemode = __any(bad_byte);    // uniform across block (every wave scans all)

    // 2b: scatter effective coefficients; mapping is bijective onto all 568 slots.
    for (int j = tid; j < NTERMS; j += 256) {
        const float av = a[j];
        const bool us = bytemode ? (((const unsigned char*)uses_self)[j] != 0)
                                 : (u32[j] != 0u);
        const bool zc = (us ? (av > 0.f) : (av < 0.f)) && (j >= 2);
        const float ae = zc ? 0.f : av;
        int dst;
        if (j == 0) {
            dst = 0;
        } else if (j < 22) {                   // linear
            dst = OFF_LX + lin_idx[j - 1];
        } else if (j < 127) {                  // drug
            const int k = j - 22;
            dst = OFF_D + drug_idx[2 * k + 1] * NXC + drug_idx[2 * k];
        } else if (j < 337) {                  // bilinear
            const int k = j - 127;
            const int i0 = bilin_idx[2 * k], i1 = bilin_idx[2 * k + 1];
            const int r = 20 * i0 - (i0 * (i0 - 1)) / 2 + (i1 - i0 - 1);
            dst = OFF_BM + 2 * r;
        } else if (j < 547) {                  // MM2
            const int k = j - 337;
            const int i0 = mm2_idx[2 * k], i1 = mm2_idx[2 * k + 1];
            const int r = 20 * i0 - (i0 * (i0 - 1)) / 2 + (i1 - i0 - 1);
            dst = OFF_BM + 2 * r + 1;
        } else {                               // hill
            dst = OFF_LY + hill_idx[j - 547];
        }
        scf[dst] = ae;
    }

    __syncthreads();   // drains vmcnt (staging DMA) + lgkmcnt (scf writes)

    // ---- Phase 3: evaluate 2 points/thread (math identical to verified kernel).
    const float* r0 = sx + tid * NFEAT;        // stride-27: 2-way bank alias = free
    const float* r1 = sx + (tid + 256) * NFEAT;

    float x0[NXC], y0[NXC], x1[NXC], y1[NXC];
    const float c0 = scf[0];
    float acc0 = c0 * r0[0];
    float acc1 = c0 * r1[0];

#pragma unroll
    for (int i = 0; i < NXC; ++i) {
        x0[i] = r0[1 + i];
        x1[i] = r1[1 + i];
        y0[i] = x0[i] * __builtin_amdgcn_rcpf(0.5f + x0[i]);
        y1[i] = x1[i] * __builtin_amdgcn_rcpf(0.5f + x1[i]);
        const float lx = scf[OFF_LX + i], ly = scf[OFF_LY + i];
        acc0 += lx * x0[i] + ly * y0[i];
        acc1 += lx * x1[i] + ly * y1[i];
    }

#pragma unroll
    for (int d = 0; d < NDR; ++d) {
        float s0 = 0.f, s1 = 0.f;
#pragma unroll
        for (int i = 0; i < NXC; ++i) {
            const float c = scf[OFF_D + d * NXC + i];
            s0 += c * x0[i];
            s1 += c * x1[i];
        }
        acc0 += r0[1 + NXC + d] * s0;
        acc1 += r1[1 + NXC + d] * s1;
    }

    // bilinear + MM2: grouped by first index i, inner over j>i (pair-lex order)
    int k = 0;
#pragma unroll
    for (int i = 0; i < NXC - 1; ++i) {
        float sB0 = 0.f, sM0 = 0.f, sB1 = 0.f, sM1 = 0.f;
#pragma unroll
        for (int jj = i + 1; jj < NXC; ++jj) {
            const float bk = scf[OFF_BM + 2 * k];
            const float mk = scf[OFF_BM + 2 * k + 1];
            sB0 += bk * x0[jj];
            sM0 += mk * x0[jj];
            sB1 += bk * x1[jj];
            sM1 += mk * x1[jj];
            ++k;
        }
        acc0 += x0[i] * sB0 + y0[i] * sM0;
        acc1 += x1[i] * sB1 + y1[i] * sM1;
    }

    out[base + tid] = acc0;
    out[base + 256 + tid] = acc1;
}

extern "C" void kernel_launch(void* const* d_in, const int* in_sizes, int n_in,
                              void* d_out, int out_size, void* d_ws, size_t ws_size,
                              hipStream_t stream) {
    (void)in_sizes; (void)n_in; (void)d_ws; (void)ws_size;
    const float* cand  = (const float*)d_in[0];
    const float* a     = (const float*)d_in[1];
    const int*   lin   = (const int*)d_in[2];
    const int*   drug  = (const int*)d_in[3];
    const int*   bilin = (const int*)d_in[4];
    const int*   mm2   = (const int*)d_in[5];
    const int*   hill  = (const int*)d_in[6];
    const void*  uses  = d_in[7];
    float* out = (float*)d_out;

    const int npts = out_size;                    // 128*2048 = 262144
    const int nblocks = npts / PTS_PER_BLOCK;     // 512
    sindy_fused<<<nblocks, 256, 0, stream>>>(cand, a, lin, drug, bilin, mm2, hill, uses, out);
}

// Round 2
// 91.444 us; speedup vs baseline: 1.1044x; 1.0514x over previous
//
#include <hip/hip_runtime.h>

// Problem constants
#define NXC 21
#define NDR 5
#define NFEAT 27          // 1 con + 21 x + 5 drug
#define NTERMS 568        // 1 + 21 + 105 + 210 + 210 + 21
// coefficient table layout (LDS, per block):
//  [0]        c0 (constant term)
//  [1..21]    LX[i]  (linear-in-x coeffs)
//  [22..42]   LY[i]  (hill coeffs, applied to y_i = x_i/(0.5+x_i))
//  [43..147]  D[d*21+i] (drug coeffs)
//  [148..567] BM interleaved: pair k (lexicographic i<j): [148+2k]=bilin, [148+2k+1]=mm2
#define OFF_LX 1
#define OFF_LY 22
#define OFF_D  43
#define OFF_BM 148
#define NCOEF  568

// 256 points per block, 128 threads, 2 points per thread.
// LDS = 27648 + 2272 = 29.9 KB -> 5 resident blocks/CU (vs 2 at 512-pt blocks):
// keeps ~4-5 independent global_load_lds streams in flight per CU so the DMA
// queue never drains at a block boundary (kernel is DMA-bound: 27.6 KB/block
// at ~10 B/cyc/CU = 2765 cyc vs ~1300 cyc compute per wave).
#define PTS_PER_BLOCK 256
#define NTHREADS 128
#define LDS_F4 ((PTS_PER_BLOCK * NFEAT) / 4)   // 1728 float4 = 27648 B

// Direct global->LDS DMA, 16 B per lane (linear dest = the supported pattern).
#define GLOBAL_TO_LDS16(gp, lp)                                              \
    __builtin_amdgcn_global_load_lds(                                        \
        (const __attribute__((address_space(1))) void*)(gp),                 \
        (__attribute__((address_space(3))) void*)(lp), 16, 0, 0)

__global__ __launch_bounds__(NTHREADS) void sindy_fused(
    const float* __restrict__ cand,
    const float* __restrict__ a,
    const int* __restrict__ lin_idx,
    const int* __restrict__ drug_idx,
    const int* __restrict__ bilin_idx,
    const int* __restrict__ mm2_idx,
    const int* __restrict__ hill_idx,
    const void* __restrict__ uses_self,
    float* __restrict__ out)
{
    __shared__ __align__(16) float sx[PTS_PER_BLOCK * NFEAT];   // 27648 B
    __shared__ __align__(16) float scf[NCOEF];                  //  2272 B

    const int tid = threadIdx.x;
    const size_t base = (size_t)blockIdx.x * PTS_PER_BLOCK;

    // ---- Phase 1: issue candidate staging (global -> LDS, no VGPR round-trip).
    // Block's region is 27648 B = 1728 float4 = 13.5 rounds of 128 lanes.
    const float4* g4 = (const float4*)(cand + base * NFEAT);   // 27648 % 16 == 0
    float4* s4 = (float4*)sx;
#pragma unroll
    for (int k = 0; k < 13; ++k) {
        const int idx = tid + k * NTHREADS;
        GLOBAL_TO_LDS16(g4 + idx, s4 + idx);
    }
    if (tid < (LDS_F4 - 13 * NTHREADS)) {     // 64 lanes = 1 full wave (wave-uniform exec)
        const int idx = tid + 13 * NTHREADS;
        GLOBAL_TO_LDS16(g4 + idx, s4 + idx);
    }

    // ---- Phase 2 (overlaps the in-flight staging): coefficient table into LDS.
    // 2a: uses_self storage detect, wave-parallel.
    //   byte storage  -> some packed word has a byte set in lanes 1..3  (>1, != 1.0f bits)
    //   int32 {0,1} / float32 bools unify: us = (word != 0).
    const unsigned int* u32 = (const unsigned int*)uses_self;
    const int lane = tid & 63;
    bool bad_byte = false;
#pragma unroll
    for (int r = 0; r < 3; ++r) {
        const int j = lane + r * 64;          // covers 0..191 >= 142 words
        if (j < NTERMS / 4) {
            const unsigned int v = u32[j];
            if (v > 1u && v != 0x3f800000u) bad_byte = true;
        }
    }
    const bool bytemode = __any(bad_byte);    // uniform across block (every wave scans all)

    // 2b: scatter effective coefficients; mapping is bijective onto all 568 slots.
    for (int j = tid; j < NTERMS; j += NTHREADS) {
        const float av = a[j];
        const bool us = bytemode ? (((const unsigned char*)uses_self)[j] != 0)
                                 : (u32[j] != 0u);
        const bool zc = (us ? (av > 0.f) : (av < 0.f)) && (j >= 2);
        const float ae = zc ? 0.f : av;
        int dst;
        if (j == 0) {
            dst = 0;
        } else if (j < 22) {                   // linear
            dst = OFF_LX + lin_idx[j - 1];
        } else if (j < 127) {                  // drug
            const int k = j - 22;
            dst = OFF_D + drug_idx[2 * k + 1] * NXC + drug_idx[2 * k];
        } else if (j < 337) {                  // bilinear
            const int k = j - 127;
            const int i0 = bilin_idx[2 * k], i1 = bilin_idx[2 * k + 1];
            const int r = 20 * i0 - (i0 * (i0 - 1)) / 2 + (i1 - i0 - 1);
            dst = OFF_BM + 2 * r;
        } else if (j < 547) {                  // MM2
            const int k = j - 337;
            const int i0 = mm2_idx[2 * k], i1 = mm2_idx[2 * k + 1];
            const int r = 20 * i0 - (i0 * (i0 - 1)) / 2 + (i1 - i0 - 1);
            dst = OFF_BM + 2 * r + 1;
        } else {                               // hill
            dst = OFF_LY + hill_idx[j - 547];
        }
        scf[dst] = ae;
    }

    __syncthreads();   // drains vmcnt (staging DMA) + lgkmcnt (scf writes)

    // ---- Phase 3: evaluate 2 points/thread (math identical to verified kernel;
    // 2 pts/thread amortizes the ~568 broadcast scf ds_reads per wave).
    const float* r0 = sx + tid * NFEAT;        // stride-27: 2-way bank alias = free
    const float* r1 = sx + (tid + NTHREADS) * NFEAT;

    float x0[NXC], y0[NXC], x1[NXC], y1[NXC];
    const float c0 = scf[0];
    float acc0 = c0 * r0[0];
    float acc1 = c0 * r1[0];

#pragma unroll
    for (int i = 0; i < NXC; ++i) {
        x0[i] = r0[1 + i];
        x1[i] = r1[1 + i];
        y0[i] = x0[i] * __builtin_amdgcn_rcpf(0.5f + x0[i]);
        y1[i] = x1[i] * __builtin_amdgcn_rcpf(0.5f + x1[i]);
        const float lx = scf[OFF_LX + i], ly = scf[OFF_LY + i];
        acc0 += lx * x0[i] + ly * y0[i];
        acc1 += lx * x1[i] + ly * y1[i];
    }

#pragma unroll
    for (int d = 0; d < NDR; ++d) {
        float s0 = 0.f, s1 = 0.f;
#pragma unroll
        for (int i = 0; i < NXC; ++i) {
            const float c = scf[OFF_D + d * NXC + i];
            s0 += c * x0[i];
            s1 += c * x1[i];
        }
        acc0 += r0[1 + NXC + d] * s0;
        acc1 += r1[1 + NXC + d] * s1;
    }

    // bilinear + MM2: grouped by first index i, inner over j>i (pair-lex order)
    int k = 0;
#pragma unroll
    for (int i = 0; i < NXC - 1; ++i) {
        float sB0 = 0.f, sM0 = 0.f, sB1 = 0.f, sM1 = 0.f;
#pragma unroll
        for (int jj = i + 1; jj < NXC; ++jj) {
            const float bk = scf[OFF_BM + 2 * k];
            const float mk = scf[OFF_BM + 2 * k + 1];
            sB0 += bk * x0[jj];
            sM0 += mk * x0[jj];
            sB1 += bk * x1[jj];
            sM1 += mk * x1[jj];
            ++k;
        }
        acc0 += x0[i] * sB0 + y0[i] * sM0;
        acc1 += x1[i] * sB1 + y1[i] * sM1;
    }

    out[base + tid] = acc0;
    out[base + NTHREADS + tid] = acc1;
}

extern "C" void kernel_launch(void* const* d_in, const int* in_sizes, int n_in,
                              void* d_out, int out_size, void* d_ws, size_t ws_size,
                              hipStream_t stream) {
    (void)in_sizes; (void)n_in; (void)d_ws; (void)ws_size;
    const float* cand  = (const float*)d_in[0];
    const float* a     = (const float*)d_in[1];
    const int*   lin   = (const int*)d_in[2];
    const int*   drug  = (const int*)d_in[3];
    const int*   bilin = (const int*)d_in[4];
    const int*   mm2   = (const int*)d_in[5];
    const int*   hill  = (const int*)d_in[6];
    const void*  uses  = d_in[7];
    float* out = (float*)d_out;

    const int npts = out_size;                    // 128*2048 = 262144
    const int nblocks = npts / PTS_PER_BLOCK;     // 1024
    sindy_fused<<<nblocks, NTHREADS, 0, stream>>>(cand, a, lin, drug, bilin, mm2, hill, uses, out);
}